// Round 13
// baseline (99.653 us; speedup 1.0000x reference)
//
#include <hip/hip_runtime.h>
#include <math.h>

#define ALPHA 5e-4f
#define BIG 1e30f

typedef __attribute__((ext_vector_type(4))) float f32x4;

// ---------------- Kernel A: f32 -> fp8(e4m3) convert + exact f32 row norms ----------------
// sqn32 = ||x_row||^2 of ORIGINAL f32 values (bias-free metric; R9-verified).
__global__ __launch_bounds__(256)
void conv_fp8_kernel(const float* __restrict__ X, unsigned char* __restrict__ Xq,
                     float* __restrict__ sqn32, int d) {
    const int w = threadIdx.x >> 6, lane = threadIdx.x & 63;
    const int row = blockIdx.x * 4 + w;
    const float4* src = reinterpret_cast<const float4*>(X + (size_t)row * d);
    int4* dst = reinterpret_cast<int4*>(Xq + (size_t)row * d);
    float s = 0.f;
    const int ng = d >> 4;                 // 16 floats / group
    for (int g = lane; g < ng; g += 64) {
        int wds[4];
#pragma unroll
        for (int q = 0; q < 4; ++q) {
            float4 v = src[g * 4 + q];
            s += v.x * v.x + v.y * v.y + v.z * v.z + v.w * v.w;
            int t0 = __builtin_amdgcn_cvt_pk_fp8_f32(v.x, v.y, 0, false);
            wds[q] = __builtin_amdgcn_cvt_pk_fp8_f32(v.z, v.w, t0, true);
        }
        dst[g] = make_int4(wds[0], wds[1], wds[2], wds[3]);
    }
    for (int off = 1; off < 64; off <<= 1) s += __shfl_xor(s, off, 64);
    if (lane == 0) sqn32[row] = s;
}

// ---------------- Kernel B: register-direct fp8 gram, 1 wave / 64x64 tile ----------------
// NO LDS, NO barriers.  For X*X^T the A-frag and B-frag of a row-slice share
// the same lane layout (lane (lc,lg) <- row lc, bytes lg*8 of the K-window),
// so frags load straight from global into VGPRs (global_load_dwordx2).
// 2080 independent 1-wave blocks; 4-deep register ring, CONSUME slot w&3
// THEN reload it with window w+3 (R12's bug: load-before-consume aliased the
// live slot).  3 windows (24 loads) in flight; compiler-placed waitcnts.
// Selection value s = sqn32[col] - 2*<xq_i,xq_j>  (bias-free metric).
// Slots per row: col-strip J contributes slot J (col-path rb / row-path cb)
// -> exactly 64 slots x 2 candidates = 128, uniform.
__global__ __launch_bounds__(64)
void gram_top2_reg(const unsigned char* __restrict__ Xq, const float* __restrict__ sqn,
                   float* __restrict__ cand_s, int* __restrict__ cand_i,
                   int n, int d, int nb, int cpx) {
    // flat XCD chunking, then triangular decode (nb = 64)
    const int bid = blockIdx.x;
    int rem = (bid & 7) * cpx + (bid >> 3);
    int rb = 0;
    while (rem >= nb - rb) { rem -= nb - rb; ++rb; }
    const int cb = rb + rem;

    const int row0 = rb * 64, col0 = cb * 64;
    const int l = threadIdx.x;
    const int lc = l & 15, lg = l >> 4;

    f32x4 acc[4][4];
#pragma unroll
    for (int i = 0; i < 4; ++i)
#pragma unroll
        for (int j = 0; j < 4; ++j) acc[i][j] = (f32x4){0.f, 0.f, 0.f, 0.f};

    const unsigned char* pa = Xq + (size_t)(row0 + lc) * d + lg * 8;
    const unsigned char* pb = Xq + (size_t)(col0 + lc) * d + lg * 8;
    const size_t mstep = (size_t)16 * d;

    long long abuf[4][4], bbuf[4][4];

#define LOADW(slot, w)                                                          \
    {                                                                           \
        _Pragma("unroll")                                                       \
        for (int mi = 0; mi < 4; ++mi) {                                        \
            abuf[slot][mi] = *reinterpret_cast<const long long*>(pa + mi * mstep + (w) * 32); \
            bbuf[slot][mi] = *reinterpret_cast<const long long*>(pb + mi * mstep + (w) * 32); \
        }                                                                       \
    }

    // prologue: windows 0,1,2 in flight (slots 0,1,2)
    LOADW(0, 0)
    LOADW(1, 1)
    LOADW(2, 2)

#pragma unroll
    for (int w = 0; w < 32; ++w) {
        const int sc = w & 3;              // consume this slot...
        __builtin_amdgcn_s_setprio(1);
#pragma unroll
        for (int mi = 0; mi < 4; ++mi)
#pragma unroll
            for (int ni = 0; ni < 4; ++ni)
                acc[mi][ni] = __builtin_amdgcn_mfma_f32_16x16x32_fp8_fp8(
                    abuf[sc][mi], bbuf[sc][ni], acc[mi][ni], 0, 0, 0);
        __builtin_amdgcn_s_setprio(0);
        if (w + 3 < 32) {                  // ...then refill the freed slot
            LOADW((w + 3) & 3, w + 3)
        }
    }
#undef LOADW

    // ---- row-path epilogue: per-row top-2 over this block's 64-col strip ----
    // C frag layout: col = lane&15, row = (lane>>4)*4 + reg.
    float sq_c[4];
#pragma unroll
    for (int ni = 0; ni < 4; ++ni) sq_c[ni] = sqn[col0 + ni * 16 + lc];

#pragma unroll
    for (int mi = 0; mi < 4; ++mi) {
#pragma unroll
        for (int j = 0; j < 4; ++j) {
            const int grow = row0 + mi * 16 + lg * 4 + j;
            float s1v = BIG, s2v = BIG;
            int i1 = -1, i2 = -1;
#pragma unroll
            for (int ni = 0; ni < 4; ++ni) {
                const int gcol = col0 + ni * 16 + lc;
                float s = sq_c[ni] - 2.f * acc[mi][ni][j];
                if (gcol == grow) s = BIG;   // exclude self (diag blocks)
                if (s < s1v) { s2v = s1v; i2 = i1; s1v = s; i1 = gcol; }
                else if (s < s2v) { s2v = s; i2 = gcol; }
            }
            for (int off = 1; off < 16; off <<= 1) {
                float b1 = __shfl_xor(s1v, off, 16);
                int  bi1 = __shfl_xor(i1, off, 16);
                float b2 = __shfl_xor(s2v, off, 16);
                int  bi2 = __shfl_xor(i2, off, 16);
                if (b1 < s1v) { s2v = s1v; i2 = i1; s1v = b1; i1 = bi1; }
                else if (b1 < s2v) { s2v = b1; i2 = bi1; }
                if (b2 < s2v) { s2v = b2; i2 = bi2; }
            }
            if (lc == 0) {
                size_t base = ((size_t)grow * 64 + cb) * 2;
                cand_s[base] = s1v; cand_s[base + 1] = s2v;
                cand_i[base] = i1; cand_i[base + 1] = i2;
            }
        }
    }

    // ---- col-path epilogue (off-diagonal blocks): per-col top-2 over 64 rows ----
    if (rb != cb) {
        float sq_r[4][4];
#pragma unroll
        for (int mi = 0; mi < 4; ++mi)
#pragma unroll
            for (int j = 0; j < 4; ++j)
                sq_r[mi][j] = sqn[row0 + mi * 16 + lg * 4 + j];

#pragma unroll
        for (int ni = 0; ni < 4; ++ni) {
            const int gcol = col0 + ni * 16 + lc;
            float s1v = BIG, s2v = BIG;
            int i1 = -1, i2 = -1;
#pragma unroll
            for (int mi = 0; mi < 4; ++mi)
#pragma unroll
                for (int j = 0; j < 4; ++j) {
                    const int grow = row0 + mi * 16 + lg * 4 + j;
                    float s = sq_r[mi][j] - 2.f * acc[mi][ni][j];
                    if (s < s1v) { s2v = s1v; i2 = i1; s1v = s; i1 = grow; }
                    else if (s < s2v) { s2v = s; i2 = grow; }
                }
#pragma unroll
            for (int off = 16; off < 64; off <<= 1) {
                float b1 = __shfl_xor(s1v, off, 64);
                int  bi1 = __shfl_xor(i1, off, 64);
                float b2 = __shfl_xor(s2v, off, 64);
                int  bi2 = __shfl_xor(i2, off, 64);
                if (b1 < s1v) { s2v = s1v; i2 = i1; s1v = b1; i1 = bi1; }
                else if (b1 < s2v) { s2v = b1; i2 = bi1; }
                if (b2 < s2v) { s2v = b2; i2 = bi2; }
            }
            if (lg == 0) {
                size_t base = ((size_t)gcol * 64 + rb) * 2;
                cand_s[base] = s1v; cand_s[base + 1] = s2v;
                cand_i[base] = i1; cand_i[base + 1] = i2;
            }
        }
    }
}

// ---------------- Kernel C: merge 128 candidates/row + edge terms ----------------
__global__ __launch_bounds__(256)
void merge_edges_kernel(const float* __restrict__ sqn,
                        const float* __restrict__ cand_s, const int* __restrict__ cand_i,
                        const int* __restrict__ yb, const float* __restrict__ yo,
                        float* __restrict__ partial, int ncls) {
    const int w = threadIdx.x >> 6, lane = threadIdx.x & 63;
    const int row = blockIdx.x * 4 + w;

    float2 cs = reinterpret_cast<const float2*>(cand_s + (size_t)row * 128)[lane];
    int2   ci = reinterpret_cast<const int2*>(cand_i + (size_t)row * 128)[lane];
    float s1 = cs.x, s2 = cs.y;
    int i1 = ci.x, i2 = ci.y;
    if (s2 < s1) { float ts = s1; s1 = s2; s2 = ts; int ti = i1; i1 = i2; i2 = ti; }

    for (int off = 1; off < 64; off <<= 1) {
        float b1 = __shfl_xor(s1, off, 64);
        int  bi1 = __shfl_xor(i1, off, 64);
        float b2 = __shfl_xor(s2, off, 64);
        int  bi2 = __shfl_xor(i2, off, 64);
        if (b1 < s1) { s2 = s1; i2 = i1; s1 = b1; i1 = bi1; }
        else if (b1 < s2) { s2 = b1; i2 = bi1; }
        if (b2 < s2) { s2 = b2; i2 = bi2; }
    }
    const int yr = yb[row];
    const float sr = sqn[row];
    float w1 = ((yr == yb[i1]) ? 1.f : -1.f) * expf(-sqrtf(fmaxf(sr + s1, 0.f)));
    float w2 = ((yr == yb[i2]) ? 1.f : -1.f) * expf(-sqrtf(fmaxf(sr + s2, 0.f)));

    const float4* yr4 = reinterpret_cast<const float4*>(yo + (size_t)row * ncls);
    const float4* y14 = reinterpret_cast<const float4*>(yo + (size_t)i1 * ncls);
    const float4* y24 = reinterpret_cast<const float4*>(yo + (size_t)i2 * ncls);
    const int nv4 = ncls >> 2;             // 250
    float a1 = 0.f, a2 = 0.f;
    for (int c = lane; c < nv4; c += 64) {
        float4 v = yr4[c];
        float4 u1 = y14[c];
        float4 u2 = y24[c];
        float tx = v.x - u1.x, ty = v.y - u1.y, tz = v.z - u1.z, tw = v.w - u1.w;
        a1 = fmaf(tx, tx, fmaf(ty, ty, fmaf(tz, tz, fmaf(tw, tw, a1))));
        tx = v.x - u2.x; ty = v.y - u2.y; tz = v.z - u2.z; tw = v.w - u2.w;
        a2 = fmaf(tx, tx, fmaf(ty, ty, fmaf(tz, tz, fmaf(tw, tw, a2))));
    }
    for (int c = (nv4 << 2) + lane; c < ncls; c += 64) {   // tail (empty for 1000)
        float v = yo[(size_t)row * ncls + c];
        float t1 = v - yo[(size_t)i1 * ncls + c];
        float t2 = v - yo[(size_t)i2 * ncls + c];
        a1 = fmaf(t1, t1, a1);
        a2 = fmaf(t2, t2, a2);
    }
    for (int off = 1; off < 64; off <<= 1) {
        a1 += __shfl_xor(a1, off, 64);
        a2 += __shfl_xor(a2, off, 64);
    }
    if (lane == 0)
        partial[row] = w1 * sqrtf(a1) + w2 * sqrtf(a2);
}

// ---------------- Kernel D: final reduction of n partials ----------------
__global__ __launch_bounds__(256)
void final_reduce_kernel(const float* __restrict__ partial, float* __restrict__ out, int n) {
    const int t = threadIdx.x;
    __shared__ float red[4];
    float s = 0.f;
    const int nv4 = n >> 2;
    const float4* p4 = reinterpret_cast<const float4*>(partial);
    for (int c = t; c < nv4; c += 256) {
        float4 v = p4[c];
        s += v.x + v.y + v.z + v.w;
    }
    for (int off = 1; off < 64; off <<= 1) s += __shfl_xor(s, off, 64);
    if ((t & 63) == 0) red[t >> 6] = s;
    __syncthreads();
    if (t == 0) out[0] = ALPHA * (red[0] + red[1] + red[2] + red[3]);
}

extern "C" void kernel_launch(void* const* d_in, const int* in_sizes, int n_in,
                              void* d_out, int out_size, void* d_ws, size_t ws_size,
                              hipStream_t stream) {
    const float* X  = (const float*)d_in[0];
    const int*   yb = (const int*)d_in[1];
    const float* yo = (const float*)d_in[2];
    float* out = (float*)d_out;

    const int n    = in_sizes[1];          // 4096
    const int d    = in_sizes[0] / n;      // 1024
    const int ncls = in_sizes[2] / n;      // 1000
    const int nb   = n / 64;               // 64 row/col blocks of 64

    // workspace: sqn32 | Xq (fp8) | cand_s | cand_i | partial
    char* wsb = (char*)d_ws;
    size_t off = 0;
    float* sqn32 = (float*)(wsb + off);         off += ((size_t)n * 4 + 255) & ~(size_t)255;
    unsigned char* Xq = (unsigned char*)(wsb + off); off += ((size_t)n * d + 255) & ~(size_t)255;
    float* cand_s = (float*)(wsb + off);        off += ((size_t)n * 64 * 2 * 4 + 255) & ~(size_t)255;
    int*   cand_i = (int*)(wsb + off);          off += ((size_t)n * 64 * 2 * 4 + 255) & ~(size_t)255;
    float* partial = (float*)(wsb + off);

    conv_fp8_kernel<<<n / 4, 256, 0, stream>>>(X, Xq, sqn32, d);

    const int ntri = nb * (nb + 1) / 2;    // 2080 = 260*8
    const int cpx  = ntri / 8;             // 260
    gram_top2_reg<<<ntri, 64, 0, stream>>>(Xq, sqn32, cand_s, cand_i, n, d, nb, cpx);

    merge_edges_kernel<<<n / 4, 256, 0, stream>>>(sqn32, cand_s, cand_i, yb, yo, partial, ncls);

    final_reduce_kernel<<<1, 256, 0, stream>>>(partial, out, n);
}

// Round 14
// 73.738 us; speedup vs baseline: 1.3514x; 1.3514x over previous
//
#include <hip/hip_runtime.h>
#include <math.h>

#define ALPHA 5e-4f
#define BIG 1e30f

typedef __attribute__((ext_vector_type(4))) float f32x4;

__device__ __forceinline__ void gload16(const void* g, void* l) {
    __builtin_amdgcn_global_load_lds(
        (const __attribute__((address_space(1))) void*)g,
        (__attribute__((address_space(3))) void*)l, 16, 0, 0);
}

// ---------------- Kernel A: f32 -> fp8(e4m3) convert + exact f32 row norms ----------------
// sqn32 = ||x_row||^2 of ORIGINAL f32 values (bias-free metric; R9-verified).
__global__ __launch_bounds__(256)
void conv_fp8_kernel(const float* __restrict__ X, unsigned char* __restrict__ Xq,
                     float* __restrict__ sqn32, int d) {
    const int w = threadIdx.x >> 6, lane = threadIdx.x & 63;
    const int row = blockIdx.x * 4 + w;
    const float4* src = reinterpret_cast<const float4*>(X + (size_t)row * d);
    int4* dst = reinterpret_cast<int4*>(Xq + (size_t)row * d);
    float s = 0.f;
    const int ng = d >> 4;                 // 16 floats / group
    for (int g = lane; g < ng; g += 64) {
        int wds[4];
#pragma unroll
        for (int q = 0; q < 4; ++q) {
            float4 v = src[g * 4 + q];
            s += v.x * v.x + v.y * v.y + v.z * v.z + v.w * v.w;
            int t0 = __builtin_amdgcn_cvt_pk_fp8_f32(v.x, v.y, 0, false);
            wds[q] = __builtin_amdgcn_cvt_pk_fp8_f32(v.z, v.w, t0, true);
        }
        dst[g] = make_int4(wds[0], wds[1], wds[2], wds[3]);
    }
    for (int off = 1; off < 64; off <<= 1) s += __shfl_xor(s, off, 64);
    if (lane == 0) sqn32[row] = s;
}

// ---------------- Kernel B: 64x64 fp8 tiles, 8 independent blocks/CU ----------------
// Triangle of 64x64 tiles = 2080 blocks (8.1/CU resident -> ~32 waves/CU of
// INDEPENDENT streams; the residency axis never exercised: best configs so far
// were pinned at 2.06 blocks/CU).  4 waves/block, wave w owns rows
// [16w,16w+16) x all 64 cols (acc[4] of f32x4).  BK=64 (16 steps), 16 KB LDS
// double-buffer, counted vmcnt(2).
// LDS swizzle (even-XOR, gload16-safe): stored 16B-slot s of row r holds
// global slot s^(r&3); source slot = (t&3)^((t>>2)&3); read global 8B-chunk g
// of row r at position g^((r&3)<<1).  Residual 4-way on ds_read_b64 (1.58x).
// Selection value s = sqn32[col] - 2*<xq_i,xq_j>  (bias-free metric).
// Slots: row-path -> slot cb; col-path (rb<cb) -> slot rb (cross-wave merged
// via 4KB LDS scratch).  Per row exactly 64 slots x 2 = 128 candidates.
__global__ __launch_bounds__(256)
void gram_top2_mfma(const unsigned char* __restrict__ Xq, const float* __restrict__ sqn,
                    float* __restrict__ cand_s, int* __restrict__ cand_i,
                    int n, int d, int nb, int cpx) {
    __shared__ unsigned char lds[2][8192];   // per buf: A 4KB | B 4KB

    // flat XCD chunking, then triangular decode (nb = 64)
    const int bid = blockIdx.x;
    int rem = (bid & 7) * cpx + (bid >> 3);
    int rb = 0;
    while (rem >= nb - rb) { rem -= nb - rb; ++rb; }
    const int cb = rb + rem;

    const int row0 = rb * 64, col0 = cb * 64;
    const int t = threadIdx.x;
    const int w = t >> 6, l = t & 63;
    const int lc = l & 15, lg = l >> 4;

    f32x4 acc[4];
#pragma unroll
    for (int j = 0; j < 4; ++j) acc[j] = (f32x4){0.f, 0.f, 0.f, 0.f};

    // staging: thread t -> tile row t>>2 (0..63), 16B slot t&3, swizzled source
    const int swz16 = ((t & 3) ^ ((t >> 2) & 3)) << 4;
    const size_t gA0 = (size_t)(row0 + (t >> 2)) * d + swz16;
    const size_t gB0 = (size_t)(col0 + (t >> 2)) * d + swz16;
    unsigned char* ldsw0 = &lds[0][w * 1024];   // wave-uniform dest bases
    unsigned char* ldsw1 = &lds[1][w * 1024];

#define STAGE(bi, ks)                                                    \
    {                                                                    \
        unsigned char* dstb = (bi) ? ldsw1 : ldsw0;                      \
        gload16(Xq + gA0 + (ks) * 64, dstb);                             \
        gload16(Xq + gB0 + (ks) * 64, dstb + 4096);                     \
    }

    STAGE(0, 0)
    int cur = 0;
    const int nsteps = 16;                   // d / 64
    const int cs = (lc & 3) << 1;            // read-side chunk XOR

    for (int ks = 0; ks < nsteps; ++ks) {
        if (ks + 1 < nsteps) {
            STAGE(cur ^ 1, ks + 1)
            asm volatile("s_waitcnt vmcnt(2)" ::: "memory");  // stage ks landed
        } else {
            asm volatile("s_waitcnt vmcnt(0)" ::: "memory");
        }
        __builtin_amdgcn_s_barrier();        // stage ks visible to all waves

        const unsigned char* base = lds[cur];
        long long av[2];
        long long bv[4][2];
#pragma unroll
        for (int kk = 0; kk < 2; ++kk) {
            const int ch = ((kk << 2) | lg) ^ cs;
            av[kk] = *reinterpret_cast<const long long*>(
                base + (w * 16 + lc) * 64 + ch * 8);
#pragma unroll
            for (int ni = 0; ni < 4; ++ni)
                bv[ni][kk] = *reinterpret_cast<const long long*>(
                    base + 4096 + (ni * 16 + lc) * 64 + ch * 8);
        }
        __builtin_amdgcn_s_setprio(1);
#pragma unroll
        for (int kk = 0; kk < 2; ++kk)
#pragma unroll
            for (int ni = 0; ni < 4; ++ni)
                acc[ni] = __builtin_amdgcn_mfma_f32_16x16x32_fp8_fp8(
                    av[kk], bv[ni][kk], acc[ni], 0, 0, 0);
        __builtin_amdgcn_s_setprio(0);

        asm volatile("s_waitcnt lgkmcnt(0)" ::: "memory");
        __builtin_amdgcn_s_barrier();        // reads of cur done -> reusable
        cur ^= 1;
    }
#undef STAGE

    // ---- row-path epilogue: per-row top-2 over all 64 cols (wave-local) ----
    // C frag layout: col = lane&15, row = (lane>>4)*4 + reg.
    float sq_c[4];
#pragma unroll
    for (int ni = 0; ni < 4; ++ni) sq_c[ni] = sqn[col0 + ni * 16 + lc];

#pragma unroll
    for (int j = 0; j < 4; ++j) {
        const int grow = row0 + w * 16 + lg * 4 + j;
        float s1v = BIG, s2v = BIG;
        int i1 = -1, i2 = -1;
#pragma unroll
        for (int ni = 0; ni < 4; ++ni) {
            const int gcol = col0 + ni * 16 + lc;
            float s = sq_c[ni] - 2.f * acc[ni][j];
            if (gcol == grow) s = BIG;       // exclude self (diag blocks)
            if (s < s1v) { s2v = s1v; i2 = i1; s1v = s; i1 = gcol; }
            else if (s < s2v) { s2v = s; i2 = gcol; }
        }
        for (int off = 1; off < 16; off <<= 1) {
            float b1 = __shfl_xor(s1v, off, 16);
            int  bi1 = __shfl_xor(i1, off, 16);
            float b2 = __shfl_xor(s2v, off, 16);
            int  bi2 = __shfl_xor(i2, off, 16);
            if (b1 < s1v) { s2v = s1v; i2 = i1; s1v = b1; i1 = bi1; }
            else if (b1 < s2v) { s2v = b1; i2 = bi1; }
            if (b2 < s2v) { s2v = b2; i2 = bi2; }
        }
        if (lc == 0) {
            size_t base = ((size_t)grow * 64 + cb) * 2;
            cand_s[base] = s1v; cand_s[base + 1] = s2v;
            cand_i[base] = i1; cand_i[base + 1] = i2;
        }
    }

    // ---- col-path epilogue (off-diag): per-col top-2, cross-wave LDS merge ----
    if (rb != cb) {
        float2* scr_s = reinterpret_cast<float2*>(&lds[0][0]);      // [4][64]
        int2*   scr_i = reinterpret_cast<int2*>(&lds[0][2048]);     // [4][64]

        float sq_r[4];
#pragma unroll
        for (int j = 0; j < 4; ++j) sq_r[j] = sqn[row0 + w * 16 + lg * 4 + j];

#pragma unroll
        for (int ni = 0; ni < 4; ++ni) {
            const int gcol0 = col0 + ni * 16 + lc;
            float s1v = BIG, s2v = BIG;
            int i1 = -1, i2 = -1;
#pragma unroll
            for (int j = 0; j < 4; ++j) {
                const int grow = row0 + w * 16 + lg * 4 + j;
                float s = sq_r[j] - 2.f * acc[ni][j];
                if (s < s1v) { s2v = s1v; i2 = i1; s1v = s; i1 = grow; }
                else if (s < s2v) { s2v = s; i2 = grow; }
            }
#pragma unroll
            for (int off = 16; off < 64; off <<= 1) {
                float b1 = __shfl_xor(s1v, off, 64);
                int  bi1 = __shfl_xor(i1, off, 64);
                float b2 = __shfl_xor(s2v, off, 64);
                int  bi2 = __shfl_xor(i2, off, 64);
                if (b1 < s1v) { s2v = s1v; i2 = i1; s1v = b1; i1 = bi1; }
                else if (b1 < s2v) { s2v = b1; i2 = bi1; }
                if (b2 < s2v) { s2v = b2; i2 = bi2; }
            }
            if (lg == 0) {
                scr_s[w * 64 + ni * 16 + lc] = make_float2(s1v, s2v);
                scr_i[w * 64 + ni * 16 + lc] = make_int2(i1, i2);
            }
            (void)gcol0;
        }
        __syncthreads();

        if (t < 64) {                        // one thread per column
            float s1v = BIG, s2v = BIG;
            int i1 = -1, i2 = -1;
#pragma unroll
            for (int ww = 0; ww < 4; ++ww) {
                float2 cs2 = scr_s[ww * 64 + t];
                int2   ci2 = scr_i[ww * 64 + t];
                if (cs2.x < s1v) { s2v = s1v; i2 = i1; s1v = cs2.x; i1 = ci2.x; }
                else if (cs2.x < s2v) { s2v = cs2.x; i2 = ci2.x; }
                if (cs2.y < s2v) { s2v = cs2.y; i2 = ci2.y; }
            }
            size_t base = ((size_t)(col0 + t) * 64 + rb) * 2;
            cand_s[base] = s1v; cand_s[base + 1] = s2v;
            cand_i[base] = i1; cand_i[base + 1] = i2;
        }
    }
}

// ---------------- Kernel C: merge 128 candidates/row + edge terms ----------------
__global__ __launch_bounds__(256)
void merge_edges_kernel(const float* __restrict__ sqn,
                        const float* __restrict__ cand_s, const int* __restrict__ cand_i,
                        const int* __restrict__ yb, const float* __restrict__ yo,
                        float* __restrict__ partial, int ncls) {
    const int w = threadIdx.x >> 6, lane = threadIdx.x & 63;
    const int row = blockIdx.x * 4 + w;

    float2 cs = reinterpret_cast<const float2*>(cand_s + (size_t)row * 128)[lane];
    int2   ci = reinterpret_cast<const int2*>(cand_i + (size_t)row * 128)[lane];
    float s1 = cs.x, s2 = cs.y;
    int i1 = ci.x, i2 = ci.y;
    if (s2 < s1) { float ts = s1; s1 = s2; s2 = ts; int ti = i1; i1 = i2; i2 = ti; }

    for (int off = 1; off < 64; off <<= 1) {
        float b1 = __shfl_xor(s1, off, 64);
        int  bi1 = __shfl_xor(i1, off, 64);
        float b2 = __shfl_xor(s2, off, 64);
        int  bi2 = __shfl_xor(i2, off, 64);
        if (b1 < s1) { s2 = s1; i2 = i1; s1 = b1; i1 = bi1; }
        else if (b1 < s2) { s2 = b1; i2 = bi1; }
        if (b2 < s2) { s2 = b2; i2 = bi2; }
    }
    const int yr = yb[row];
    const float sr = sqn[row];
    float w1 = ((yr == yb[i1]) ? 1.f : -1.f) * expf(-sqrtf(fmaxf(sr + s1, 0.f)));
    float w2 = ((yr == yb[i2]) ? 1.f : -1.f) * expf(-sqrtf(fmaxf(sr + s2, 0.f)));

    const float4* yr4 = reinterpret_cast<const float4*>(yo + (size_t)row * ncls);
    const float4* y14 = reinterpret_cast<const float4*>(yo + (size_t)i1 * ncls);
    const float4* y24 = reinterpret_cast<const float4*>(yo + (size_t)i2 * ncls);
    const int nv4 = ncls >> 2;             // 250
    float a1 = 0.f, a2 = 0.f;
    for (int c = lane; c < nv4; c += 64) {
        float4 v = yr4[c];
        float4 u1 = y14[c];
        float4 u2 = y24[c];
        float tx = v.x - u1.x, ty = v.y - u1.y, tz = v.z - u1.z, tw = v.w - u1.w;
        a1 = fmaf(tx, tx, fmaf(ty, ty, fmaf(tz, tz, fmaf(tw, tw, a1))));
        tx = v.x - u2.x; ty = v.y - u2.y; tz = v.z - u2.z; tw = v.w - u2.w;
        a2 = fmaf(tx, tx, fmaf(ty, ty, fmaf(tz, tz, fmaf(tw, tw, a2))));
    }
    for (int c = (nv4 << 2) + lane; c < ncls; c += 64) {   // tail (empty for 1000)
        float v = yo[(size_t)row * ncls + c];
        float t1 = v - yo[(size_t)i1 * ncls + c];
        float t2 = v - yo[(size_t)i2 * ncls + c];
        a1 = fmaf(t1, t1, a1);
        a2 = fmaf(t2, t2, a2);
    }
    for (int off = 1; off < 64; off <<= 1) {
        a1 += __shfl_xor(a1, off, 64);
        a2 += __shfl_xor(a2, off, 64);
    }
    if (lane == 0)
        partial[row] = w1 * sqrtf(a1) + w2 * sqrtf(a2);
}

// ---------------- Kernel D: final reduction of n partials ----------------
__global__ __launch_bounds__(256)
void final_reduce_kernel(const float* __restrict__ partial, float* __restrict__ out, int n) {
    const int t = threadIdx.x;
    __shared__ float red[4];
    float s = 0.f;
    const int nv4 = n >> 2;
    const float4* p4 = reinterpret_cast<const float4*>(partial);
    for (int c = t; c < nv4; c += 256) {
        float4 v = p4[c];
        s += v.x + v.y + v.z + v.w;
    }
    for (int off = 1; off < 64; off <<= 1) s += __shfl_xor(s, off, 64);
    if ((t & 63) == 0) red[t >> 6] = s;
    __syncthreads();
    if (t == 0) out[0] = ALPHA * (red[0] + red[1] + red[2] + red[3]);
}

extern "C" void kernel_launch(void* const* d_in, const int* in_sizes, int n_in,
                              void* d_out, int out_size, void* d_ws, size_t ws_size,
                              hipStream_t stream) {
    const float* X  = (const float*)d_in[0];
    const int*   yb = (const int*)d_in[1];
    const float* yo = (const float*)d_in[2];
    float* out = (float*)d_out;

    const int n    = in_sizes[1];          // 4096
    const int d    = in_sizes[0] / n;      // 1024
    const int ncls = in_sizes[2] / n;      // 1000
    const int nb   = n / 64;               // 64 row/col blocks of 64

    // workspace: sqn32 | Xq (fp8) | cand_s | cand_i | partial
    char* wsb = (char*)d_ws;
    size_t off = 0;
    float* sqn32 = (float*)(wsb + off);         off += ((size_t)n * 4 + 255) & ~(size_t)255;
    unsigned char* Xq = (unsigned char*)(wsb + off); off += ((size_t)n * d + 255) & ~(size_t)255;
    float* cand_s = (float*)(wsb + off);        off += ((size_t)n * 64 * 2 * 4 + 255) & ~(size_t)255;
    int*   cand_i = (int*)(wsb + off);          off += ((size_t)n * 64 * 2 * 4 + 255) & ~(size_t)255;
    float* partial = (float*)(wsb + off);

    conv_fp8_kernel<<<n / 4, 256, 0, stream>>>(X, Xq, sqn32, d);

    const int ntri = nb * (nb + 1) / 2;    // 2080 = 260*8
    const int cpx  = ntri / 8;             // 260
    gram_top2_mfma<<<ntri, 256, 0, stream>>>(Xq, sqn32, cand_s, cand_i, n, d, nb, cpx);

    merge_edges_kernel<<<n / 4, 256, 0, stream>>>(sqn32, cand_s, cand_i, yb, yo, partial, ncls);

    final_reduce_kernel<<<1, 256, 0, stream>>>(partial, out, n);
}

// Round 15
// 58.766 us; speedup vs baseline: 1.6958x; 1.2548x over previous
//
#include <hip/hip_runtime.h>
#include <math.h>

#define ALPHA 5e-4f
#define BIG 1e30f

typedef __attribute__((ext_vector_type(4))) float f32x4;

__device__ __forceinline__ void gload16(const void* g, void* l) {
    __builtin_amdgcn_global_load_lds(
        (const __attribute__((address_space(1))) void*)g,
        (__attribute__((address_space(3))) void*)l, 16, 0, 0);
}

// ---------------- Kernel A: f32 -> fp8(e4m3) convert + exact f32 row norms ----------------
// sqn32 = ||x_row||^2 of ORIGINAL f32 values (bias-free metric; R9-verified).
__global__ __launch_bounds__(256)
void conv_fp8_kernel(const float* __restrict__ X, unsigned char* __restrict__ Xq,
                     float* __restrict__ sqn32, int d) {
    const int w = threadIdx.x >> 6, lane = threadIdx.x & 63;
    const int row = blockIdx.x * 4 + w;
    const float4* src = reinterpret_cast<const float4*>(X + (size_t)row * d);
    int4* dst = reinterpret_cast<int4*>(Xq + (size_t)row * d);
    float s = 0.f;
    const int ng = d >> 4;                 // 16 floats / group
    for (int g = lane; g < ng; g += 64) {
        int wds[4];
#pragma unroll
        for (int q = 0; q < 4; ++q) {
            float4 v = src[g * 4 + q];
            s += v.x * v.x + v.y * v.y + v.z * v.z + v.w * v.w;
            int t0 = __builtin_amdgcn_cvt_pk_fp8_f32(v.x, v.y, 0, false);
            wds[q] = __builtin_amdgcn_cvt_pk_fp8_f32(v.z, v.w, t0, true);
        }
        dst[g] = make_int4(wds[0], wds[1], wds[2], wds[3]);
    }
    for (int off = 1; off < 64; off <<= 1) s += __shfl_xor(s, off, 64);
    if (lane == 0) sqn32[row] = s;
}

// ---------------- Kernel B: fp8 MFMA gram, FULL SQUARE 1024 blocks ----------------
// R15: grid = 32x32 = 1024 blocks of 128x128 -> EXACTLY 4 resident blocks/CU
// with zero tail (1024 = 8 XCD x 128 = 32 CU x 4).  Measured invariant:
// staging ~5 B/cy per resident block; aggregate scales with blocks/CU (m97's
// 4/CU grid = 13 TB/s).  The 528-block triangle was pinned at 2.06/CU + a
// ragged tail -- that grid size, not bytes/steps/waves, was the limiter.
// Kernel body = R9's verified fp8 BKB=64 structure, double-buffered (32 KB),
// counted vmcnt(4).  Row-path epilogue only (full square covers every
// (row, col-strip) exactly once): uniform slots cb*2+wc, 64 per row.
#define BM 128
#define BN 128
#define BKB 64

__global__ __launch_bounds__(256, 4)
void gram_top2_mfma(const unsigned char* __restrict__ Xq, const float* __restrict__ sqn,
                    float* __restrict__ cand_s, int* __restrict__ cand_i,
                    int n, int d, int nbc, int cpx) {
    __shared__ unsigned char As[2][BM * BKB];   // 2 x 8KB
    __shared__ unsigned char Bs[2][BN * BKB];   // 2 x 8KB

    // XCD chunking: 128 consecutive tiles per XCD -> rb in [x*4, x*4+4)
    const int bid = blockIdx.x;
    const int swz = (bid & 7) * cpx + (bid >> 3);
    const int rb = swz >> 5, cb = swz & 31;     // nbc = 32

    const int row0 = rb * BM, col0 = cb * BN;
    const int t = threadIdx.x;
    const int w = t >> 6, l = t & 63;
    const int wr = w >> 1, wc = w & 1;
    const int lc = l & 15, lg = l >> 4;

    f32x4 acc[4][4];
#pragma unroll
    for (int i = 0; i < 4; ++i)
#pragma unroll
        for (int j = 0; j < 4; ++j) acc[i][j] = (f32x4){0.f, 0.f, 0.f, 0.f};

    // staging (R9-verified): thread t -> row t>>2 (0..63) and +64; 16B quarter
    // (t&3) pre-swizzled: source chunk = (t&3)^((t>>3)&3).
    const int gsw = ((t & 3) ^ ((t >> 3) & 3)) << 4;
    const size_t gA0 = (size_t)(row0 + (t >> 2)) * d + gsw;
    const size_t gB0 = (size_t)(col0 + (t >> 2)) * d + gsw;
    const size_t rstep = (size_t)64 * d;
    const int wbase = w * 1024;
    const int rsw = ((lc >> 1) & 3) << 1;       // read-side chunk XOR

    const int nsteps = d / BKB;                 // 16

#define STAGE(stg, ks)                                            \
    {                                                             \
        const size_t ko = (size_t)(ks) * BKB;                     \
        gload16(Xq + gA0 + ko, As[stg] + wbase);                  \
        gload16(Xq + gA0 + ko + rstep, As[stg] + wbase + 4096);   \
        gload16(Xq + gB0 + ko, Bs[stg] + wbase);                  \
        gload16(Xq + gB0 + ko + rstep, Bs[stg] + wbase + 4096);   \
    }

    STAGE(0, 0)
    int cur = 0;
    for (int ks = 0; ks < nsteps; ++ks) {
        if (ks + 1 < nsteps) {
            STAGE(cur ^ 1, ks + 1)
            asm volatile("s_waitcnt vmcnt(4)" ::: "memory");   // stage ks landed
        } else {
            asm volatile("s_waitcnt vmcnt(0)" ::: "memory");
        }
        __builtin_amdgcn_s_barrier();      // stage ks visible to all waves

        long long a[2][4], b[2][4];
#pragma unroll
        for (int ki = 0; ki < 2; ++ki) {
            const int ch = ((ki * 4 + lg) ^ rsw) * 8;
#pragma unroll
            for (int mi = 0; mi < 4; ++mi) {
                a[ki][mi] = *reinterpret_cast<const long long*>(
                    &As[cur][(wr * 64 + mi * 16 + lc) * 64 + ch]);
                b[ki][mi] = *reinterpret_cast<const long long*>(
                    &Bs[cur][(wc * 64 + mi * 16 + lc) * 64 + ch]);
            }
        }
        __builtin_amdgcn_s_setprio(1);
#pragma unroll
        for (int mi = 0; mi < 4; ++mi)
#pragma unroll
            for (int ni = 0; ni < 4; ++ni) {
                acc[mi][ni] = __builtin_amdgcn_mfma_f32_16x16x32_fp8_fp8(
                    a[0][mi], b[0][ni], acc[mi][ni], 0, 0, 0);
                acc[mi][ni] = __builtin_amdgcn_mfma_f32_16x16x32_fp8_fp8(
                    a[1][mi], b[1][ni], acc[mi][ni], 0, 0, 0);
            }
        __builtin_amdgcn_s_setprio(0);

        asm volatile("s_waitcnt lgkmcnt(0)" ::: "memory");
        __builtin_amdgcn_s_barrier();      // reads of cur done -> cur reusable
        cur ^= 1;
    }
#undef STAGE

    // ---- row-path epilogue: per-row top-2 over this wave's 64-col strip ----
    // C frag layout: col = lane&15, row = (lane>>4)*4 + reg.
    float sq_c[4];
#pragma unroll
    for (int ni = 0; ni < 4; ++ni) sq_c[ni] = sqn[col0 + wc * 64 + ni * 16 + lc];
    const int strip_r = cb * 2 + wc;

#pragma unroll
    for (int mi = 0; mi < 4; ++mi) {
#pragma unroll
        for (int j = 0; j < 4; ++j) {
            const int grow = row0 + wr * 64 + mi * 16 + lg * 4 + j;
            float s1v = BIG, s2v = BIG;
            int i1 = -1, i2 = -1;
#pragma unroll
            for (int ni = 0; ni < 4; ++ni) {
                const int gcol = col0 + wc * 64 + ni * 16 + lc;
                float s = sq_c[ni] - 2.f * acc[mi][ni][j];
                if (gcol == grow) s = BIG;   // exclude self (diag blocks)
                if (s < s1v) { s2v = s1v; i2 = i1; s1v = s; i1 = gcol; }
                else if (s < s2v) { s2v = s; i2 = gcol; }
            }
            for (int off = 1; off < 16; off <<= 1) {
                float b1 = __shfl_xor(s1v, off, 16);
                int  bi1 = __shfl_xor(i1, off, 16);
                float b2 = __shfl_xor(s2v, off, 16);
                int  bi2 = __shfl_xor(i2, off, 16);
                if (b1 < s1v) { s2v = s1v; i2 = i1; s1v = b1; i1 = bi1; }
                else if (b1 < s2v) { s2v = b1; i2 = bi1; }
                if (b2 < s2v) { s2v = b2; i2 = bi2; }
            }
            if (lc == 0) {
                size_t base = ((size_t)grow * 64 + strip_r) * 2;
                cand_s[base] = s1v; cand_s[base + 1] = s2v;
                cand_i[base] = i1; cand_i[base + 1] = i2;
            }
        }
    }
}

// ---------------- Kernel C: merge 128 candidates/row + edge terms ----------------
__global__ __launch_bounds__(256)
void merge_edges_kernel(const float* __restrict__ sqn,
                        const float* __restrict__ cand_s, const int* __restrict__ cand_i,
                        const int* __restrict__ yb, const float* __restrict__ yo,
                        float* __restrict__ partial, int ncls) {
    const int w = threadIdx.x >> 6, lane = threadIdx.x & 63;
    const int row = blockIdx.x * 4 + w;

    float2 cs = reinterpret_cast<const float2*>(cand_s + (size_t)row * 128)[lane];
    int2   ci = reinterpret_cast<const int2*>(cand_i + (size_t)row * 128)[lane];
    float s1 = cs.x, s2 = cs.y;
    int i1 = ci.x, i2 = ci.y;
    if (s2 < s1) { float ts = s1; s1 = s2; s2 = ts; int ti = i1; i1 = i2; i2 = ti; }

    for (int off = 1; off < 64; off <<= 1) {
        float b1 = __shfl_xor(s1, off, 64);
        int  bi1 = __shfl_xor(i1, off, 64);
        float b2 = __shfl_xor(s2, off, 64);
        int  bi2 = __shfl_xor(i2, off, 64);
        if (b1 < s1) { s2 = s1; i2 = i1; s1 = b1; i1 = bi1; }
        else if (b1 < s2) { s2 = b1; i2 = bi1; }
        if (b2 < s2) { s2 = b2; i2 = bi2; }
    }
    const int yr = yb[row];
    const float sr = sqn[row];
    float w1 = ((yr == yb[i1]) ? 1.f : -1.f) * expf(-sqrtf(fmaxf(sr + s1, 0.f)));
    float w2 = ((yr == yb[i2]) ? 1.f : -1.f) * expf(-sqrtf(fmaxf(sr + s2, 0.f)));

    const float4* yr4 = reinterpret_cast<const float4*>(yo + (size_t)row * ncls);
    const float4* y14 = reinterpret_cast<const float4*>(yo + (size_t)i1 * ncls);
    const float4* y24 = reinterpret_cast<const float4*>(yo + (size_t)i2 * ncls);
    const int nv4 = ncls >> 2;             // 250
    float a1 = 0.f, a2 = 0.f;
    for (int c = lane; c < nv4; c += 64) {
        float4 v = yr4[c];
        float4 u1 = y14[c];
        float4 u2 = y24[c];
        float tx = v.x - u1.x, ty = v.y - u1.y, tz = v.z - u1.z, tw = v.w - u1.w;
        a1 = fmaf(tx, tx, fmaf(ty, ty, fmaf(tz, tz, fmaf(tw, tw, a1))));
        tx = v.x - u2.x; ty = v.y - u2.y; tz = v.z - u2.z; tw = v.w - u2.w;
        a2 = fmaf(tx, tx, fmaf(ty, ty, fmaf(tz, tz, fmaf(tw, tw, a2))));
    }
    for (int c = (nv4 << 2) + lane; c < ncls; c += 64) {   // tail (empty for 1000)
        float v = yo[(size_t)row * ncls + c];
        float t1 = v - yo[(size_t)i1 * ncls + c];
        float t2 = v - yo[(size_t)i2 * ncls + c];
        a1 = fmaf(t1, t1, a1);
        a2 = fmaf(t2, t2, a2);
    }
    for (int off = 1; off < 64; off <<= 1) {
        a1 += __shfl_xor(a1, off, 64);
        a2 += __shfl_xor(a2, off, 64);
    }
    if (lane == 0)
        partial[row] = w1 * sqrtf(a1) + w2 * sqrtf(a2);
}

// ---------------- Kernel D: final reduction of n partials ----------------
__global__ __launch_bounds__(256)
void final_reduce_kernel(const float* __restrict__ partial, float* __restrict__ out, int n) {
    const int t = threadIdx.x;
    __shared__ float red[4];
    float s = 0.f;
    const int nv4 = n >> 2;
    const float4* p4 = reinterpret_cast<const float4*>(partial);
    for (int c = t; c < nv4; c += 256) {
        float4 v = p4[c];
        s += v.x + v.y + v.z + v.w;
    }
    for (int off = 1; off < 64; off <<= 1) s += __shfl_xor(s, off, 64);
    if ((t & 63) == 0) red[t >> 6] = s;
    __syncthreads();
    if (t == 0) out[0] = ALPHA * (red[0] + red[1] + red[2] + red[3]);
}

extern "C" void kernel_launch(void* const* d_in, const int* in_sizes, int n_in,
                              void* d_out, int out_size, void* d_ws, size_t ws_size,
                              hipStream_t stream) {
    const float* X  = (const float*)d_in[0];
    const int*   yb = (const int*)d_in[1];
    const float* yo = (const float*)d_in[2];
    float* out = (float*)d_out;

    const int n    = in_sizes[1];          // 4096
    const int d    = in_sizes[0] / n;      // 1024
    const int ncls = in_sizes[2] / n;      // 1000
    const int nbc  = n / BM;               // 32

    // workspace: sqn32 | Xq (fp8) | cand_s | cand_i | partial
    char* wsb = (char*)d_ws;
    size_t off = 0;
    float* sqn32 = (float*)(wsb + off);         off += ((size_t)n * 4 + 255) & ~(size_t)255;
    unsigned char* Xq = (unsigned char*)(wsb + off); off += ((size_t)n * d + 255) & ~(size_t)255;
    float* cand_s = (float*)(wsb + off);        off += ((size_t)n * 64 * 2 * 4 + 255) & ~(size_t)255;
    int*   cand_i = (int*)(wsb + off);          off += ((size_t)n * 64 * 2 * 4 + 255) & ~(size_t)255;
    float* partial = (float*)(wsb + off);

    conv_fp8_kernel<<<n / 4, 256, 0, stream>>>(X, Xq, sqn32, d);

    const int nsq = nbc * nbc;             // 1024 = 128*8 -> 4 blocks/CU, no tail
    const int cpx = nsq / 8;               // 128
    gram_top2_mfma<<<nsq, 256, 0, stream>>>(Xq, sqn32, cand_s, cand_i, n, d, nbc, cpx);

    merge_edges_kernel<<<n / 4, 256, 0, stream>>>(sqn32, cand_s, cand_i, yb, yo, partial, ncls);

    final_reduce_kernel<<<1, 256, 0, stream>>>(partial, out, n);
}